// Round 12
// baseline (222.506 us; speedup 1.0000x reference)
//
#include <hip/hip_runtime.h>
#include <hip/hip_bf16.h>

using bf16 = __hip_bfloat16;
typedef __attribute__((ext_vector_type(8))) short bf16x8;   // 8 bf16 in 4 VGPRs
typedef __attribute__((ext_vector_type(4))) short bf16x4;   // 4 bf16 in 2 VGPRs
typedef __attribute__((ext_vector_type(4))) float f32x4;

// async global->LDS, 16B per lane; LDS dest = wave-uniform base + lane*16
typedef const __attribute__((address_space(1))) void* as1_t;
typedef __attribute__((address_space(3))) void* as3_t;
__device__ __forceinline__ void load_lds16(const void* g, void* l) {
    __builtin_amdgcn_global_load_lds((as1_t)g, (as3_t)l, 16, 0, 0);
}

// exp2 as a single v_exp_f32 via COMPILER-VISIBLE builtin (verified v11: -12us, exact)
#if !__has_builtin(__builtin_amdgcn_exp2f)
extern "C" __device__ float __ocml_native_exp2_f32(float);
#endif
__device__ __forceinline__ float exp2_fast(float x) {
#if __has_builtin(__builtin_amdgcn_exp2f)
    return __builtin_amdgcn_exp2f(x);
#else
    return __ocml_native_exp2_f32(x);
#endif
}

// ---------------- merged prolog: x cast (blocks 0..8191) + 4 weight transposes ----------------
__global__ __launch_bounds__(256) void prolog_kernel(const float* __restrict__ x,
                                                     const float* __restrict__ wq,
                                                     const float* __restrict__ wk,
                                                     const float* __restrict__ wv,
                                                     const float* __restrict__ wo,
                                                     bf16* __restrict__ xb,
                                                     bf16* __restrict__ wqkvT,
                                                     bf16* __restrict__ woT) {
    __shared__ float tile[32][33];
    const int bxg = blockIdx.x;
    if (bxg < 8192) {
        // ---- cast f32 -> bf16 (x), 4 floats/thread ----
        const int i = bxg * 256 + threadIdx.x;
        const float4 v = *(const float4*)(x + (long)i * 4);
        bf16 t[4];
        t[0] = __float2bfloat16(v.x);
        t[1] = __float2bfloat16(v.y);
        t[2] = __float2bfloat16(v.z);
        t[3] = __float2bfloat16(v.w);
        *(uint2*)(xb + (long)i * 4) = *(uint2*)t;
        return;
    }
    // ---- transpose-cast: src[K=1024][N] f32 -> dst[N][1024] bf16 ----
    const int tcb = bxg - 8192;          // 0..2559
    const int bx  = tcb >> 5;            // 0..79
    const int k0  = (tcb & 31) * 32;
    const float* src; bf16* dst; int N, n0;
    if (bx < 32)      { src = wq; dst = wqkvT;              N = 1024; n0 = bx * 32; }
    else if (bx < 40) { src = wk; dst = wqkvT + 1024*1024;  N = 256;  n0 = (bx - 32) * 32; }
    else if (bx < 48) { src = wv; dst = wqkvT + 1280*1024;  N = 256;  n0 = (bx - 40) * 32; }
    else              { src = wo; dst = woT;                N = 1024; n0 = (bx - 48) * 32; }
    const int tx = threadIdx.x & 31;
    const int ty = threadIdx.x >> 5;   // 0..7
    for (int i = 0; i < 32; i += 8)
        tile[ty + i][tx] = src[(long)(k0 + ty + i) * N + n0 + tx];
    __syncthreads();
    for (int i = 0; i < 32; i += 8)
        dst[(long)(n0 + ty + i) * 1024 + k0 + tx] = __float2bfloat16(tile[tx][ty + i]);
}

// ---------------- GEMM v17 (unchanged): v14 loop + fused V^T epilogue ----------------
template <bool BF16_OUT, bool V_SPLIT>
__global__ __launch_bounds__(256) void gemm_bt(const bf16* __restrict__ A,
                                               const bf16* __restrict__ Bt,
                                               void* __restrict__ C,
                                               bf16* __restrict__ vt,
                                               int M, int N, int K) {
    __shared__ bf16 Ash[128 * 64];
    __shared__ bf16 Bsh[128 * 64];
    const int tid  = threadIdx.x;
    const int lane = tid & 63;
    const int wid  = tid >> 6;
    const int wm   = (wid >> 1) * 64;
    const int wn   = (wid & 1) * 64;
    const int quad = lane >> 4;
    const int l16  = lane & 15;

    // XCD-chunked swizzle (T1, bijective): XCD x owns swz in [x*per, (x+1)*per)
    const int nbn = N >> 7;
    const int nwg = (M >> 7) * nbn;
    const int per = nwg >> 3;
    const int wg  = blockIdx.x;
    const int swz = (wg & 7) * per + (wg >> 3);
    const int bm  = swz / nbn;          // bn innermost within each XCD chunk
    const int bn  = swz - bm * nbn;

    // staging: 4 rows/thread/matrix (rows rS+32m), 8 gload_lds per K-iter
    const int rS  = tid >> 3;                  // 0..31
    const int chS = tid & 7;                   // linear dest chunk
    const int gch = (chS ^ (rS & 7)) * 8;      // pre-swizzled source chunk (involution)

    const bf16* pa = A  + (long)(bm * 128 + rS) * K + gch;
    const bf16* pb = Bt + (long)(bn * 128 + rS) * K + gch;
    // wave-uniform LDS bases: wave w writes rows w*8..w*8+7 (+32m), lane*16B linear
    bf16* laB = Ash + (wid << 9);
    bf16* lbB = Bsh + (wid << 9);

    f32x4 acc[4][4] = {};

    for (int k0 = 0; k0 < K; k0 += 64) {
        __syncthreads();
#pragma unroll
        for (int m = 0; m < 4; m++) {
            load_lds16(pa + k0 + (long)(32 * m) * K, laB + m * 2048);
            load_lds16(pb + k0 + (long)(32 * m) * K, lbB + m * 2048);
        }
        __syncthreads();

#pragma unroll
        for (int kf = 0; kf < 2; kf++) {
            const int sw = ((kf * 4 + quad) ^ (l16 & 7)) * 8;
            bf16x8 af[4], bfr[4];
#pragma unroll
            for (int i = 0; i < 4; i++) af[i]  = *(const bf16x8*)&Ash[(wm + i * 16 + l16) * 64 + sw];
#pragma unroll
            for (int j = 0; j < 4; j++) bfr[j] = *(const bf16x8*)&Bsh[(wn + j * 16 + l16) * 64 + sw];
#pragma unroll
            for (int i = 0; i < 4; i++)
#pragma unroll
                for (int j = 0; j < 4; j++)
                    acc[i][j] = __builtin_amdgcn_mfma_f32_16x16x32_bf16(af[i], bfr[j], acc[i][j], 0, 0, 0);
        }
    }

    if (V_SPLIT && bn >= 10) {
        // ---- V columns: write vt[b*4+kvh][d][t] transposed, skip qkv ----
        const int kvh = (bn - 10) * 2 + (wn >> 6);
        const int bq  = bm >> 4;                 // batch index
        const int t0b = (bm & 15) * 128 + wm;    // token base within batch
        bf16* vbase = vt + ((long)(bq * 4 + kvh) * 64) * 2048;
#pragma unroll
        for (int i = 0; i < 4; i++) {
#pragma unroll
            for (int j = 0; j < 4; j++) {
                const int d  = j * 16 + l16;
                const int t0 = t0b + i * 16 + quad * 4;
                bf16 t4[4];
#pragma unroll
                for (int r = 0; r < 4; r++) t4[r] = __float2bfloat16(acc[i][j][r]);
                *(uint2*)(vbase + (long)d * 2048 + t0) = *(uint2*)t4;
            }
        }
        return;
    }

#pragma unroll
    for (int i = 0; i < 4; i++) {
#pragma unroll
        for (int r = 0; r < 4; r++) {
            const long row = (long)(bm * 128 + wm + i * 16 + quad * 4 + r);
#pragma unroll
            for (int j = 0; j < 4; j++) {
                const int col = bn * 128 + wn + j * 16 + l16;
                const float v = acc[i][j][r];
                if (BF16_OUT) ((bf16*)C)[row * N + col] = __float2bfloat16(v);
                else          ((float*)C)[row * N + col] = v;
            }
        }
    }
}

// ---------------- flash attention v14: v13 + PV at K=32 (lane-local slot remap) ----------------
// ONE change vs v13 (68.4us passing): PV/l MFMAs widened 16x16x16 -> 16x16x32 by pairing
// kvt {2p, 2p+1}. The MFMA dot product is k-permutation-invariant, so we map k-slot
// quad*8+e to kv = p*32 + (e<4?0:16) + quad*4 + (e&3): B-frag (pk8) = concat of the
// lane's OWN two per-kvt packs (no cross-lane exchange); A-frag (V) = the SAME two b64
// LDS reads as old kvt=2p,2p+1 (chunk formula identical: p*4+half*2+vq == old kvt*2+vq).
// Matrix-op issue/iter 28 -> 18, o[dt] dependency chain halved (4 -> 2 accumulates/iter).
// Same MACs, same LDS traffic/banks, same exp/pack count -> absmax within threshold.
__global__ __launch_bounds__(256) void attn_kernel(const bf16* __restrict__ qkv,
                                                   const bf16* __restrict__ vt,
                                                   bf16* __restrict__ attn) {
    __shared__ bf16 Ksh[2][64 * 64];  // [buf][kv][d], chunk ^= kv&7
    __shared__ bf16 Vsh[2][64 * 64];  // [buf][d][kv], chunk ^= d&7

    const int tid  = threadIdx.x;
    const int lane = tid & 63;
    const int wid  = tid >> 6;
    const int quad = lane >> 4;
    const int l16  = lane & 15;
    const int h    = blockIdx.y;
    const int b    = blockIdx.z;
    const int kvh  = h >> 2;
    const int pb   = blockIdx.x;      // 0..15

    const float ls = 0.125f * 1.44269504f;   // 1/sqrt(64) * log2(e)

    // ones fragment (bf16x8) for l-accumulation MFMA at K=32 (A[m][k] = 1.0)
    bf16x8 ones8;
    { short o1 = (short)0x3F80; short t8o[8] = {o1,o1,o1,o1,o1,o1,o1,o1}; ones8 = *(const bf16x8*)t8o; }

    const bf16* kg = qkv + (long)(b * 2048) * 1536 + 1024 + kvh * 64;
    const bf16* vg = vt + (long)(b * 4 + kvh) * 64 * 2048;
    const int r0 = tid >> 3;          // 0..31
    const int ch0 = tid & 7;          // source 16B chunk 0..7
    const int c0 = ch0 * 8;

    const bf16* kp0 = kg + (long)r0 * 1536 + c0;
    const bf16* kp1 = kp0 + (long)32 * 1536;
    const bf16* vp0 = vg + (long)r0 * 2048 + c0;
    const bf16* vp1 = vp0 + (long)32 * 2048;

    // swizzled LDS write offsets (elements); (r0+32)&7 == r0&7
    const int wo0 = r0 * 64 + ((ch0 ^ (r0 & 7)) * 8);
    const int wo1 = wo0 + 32 * 64;
    // swizzled read address lane-constants
    const int kchunkA = (quad ^ (l16 & 7)) * 8;         // kf=0: chunk = quad
    const int kchunkB = ((4 + quad) ^ (l16 & 7)) * 8;   // kf=1: chunk = 4+quad
    const int vsub    = (quad & 1) * 4;                 // low/high half of 8-elem chunk
    const int vq      = quad >> 1;

#pragma unroll 1
    for (int seg = 0; seg < 2; ++seg) {
        const int qb     = seg ? pb : (31 - pb);
        const int qblock = qb * 64;
        const int q0     = qblock + wid * 16;

        // Q fragment (B-operand for S^T): n=q=l16, k=d=kf*32+quad*8+e; pre-scaled by ls
        const bf16* qbase = qkv + (long)(b * 2048 + q0 + l16) * 1536 + h * 64;
        bf16x8 qf[2];
#pragma unroll
        for (int kf = 0; kf < 2; kf++) {
            const bf16* qp = qbase + kf * 32 + quad * 8;
            bf16 t8[8];
#pragma unroll
            for (int e = 0; e < 8; e++) t8[e] = __float2bfloat16(__bfloat162float(qp[e]) * ls);
            qf[kf] = *(const bf16x8*)t8;
        }

        f32x4 o[4] = {};          // O^T: q=l16, d = dt*16 + quad*4 + r
        f32x4 ol = {};            // l accumulator: every element = sum_kv P[kv][q=l16]

        // prologue: prefetch tile 0 of this segment
        uint4 kr0 = *(const uint4*)kp0;
        uint4 kr1 = *(const uint4*)kp1;
        uint4 vr0 = *(const uint4*)vp0;
        uint4 vr1 = *(const uint4*)vp1;

        __syncthreads();   // segment boundary: prior segment's reads of both buffers done

        const int nIter = qb + 1;
        for (int it = 0; it < nIter; ++it) {
            bf16* __restrict__ Kb = &Ksh[it & 1][0];
            bf16* __restrict__ Vb = &Vsh[it & 1][0];
            *(uint4*)&Kb[wo0] = kr0;
            *(uint4*)&Kb[wo1] = kr1;
            *(uint4*)&Vb[wo0] = vr0;
            *(uint4*)&Vb[wo1] = vr1;
            __syncthreads();   // single barrier per iter; dbuf covers the WAR side

            // ---- prefetch tile it+1 (hides under compute below) ----
            if (it + 1 < nIter) {
                const long ko = (long)(it + 1) * 64 * 1536;
                const long vo = (it + 1) * 64;
                kr0 = *(const uint4*)(kp0 + ko);
                kr1 = *(const uint4*)(kp1 + ko);
                vr0 = *(const uint4*)(vp0 + vo);
                vr1 = *(const uint4*)(vp1 + vo);
            }

            // ---- S^T = K Q^T : s[kvt]: q=l16, kv = it*64 + kvt*16 + quad*4 + r ----
            f32x4 s[4] = {};
            __builtin_amdgcn_s_setprio(1);
#pragma unroll
            for (int kvt = 0; kvt < 4; kvt++)
#pragma unroll
                for (int kf = 0; kf < 2; kf++) {
                    const int rbase = (kvt * 16 + l16) * 64;
                    const bf16x8 kfr = *(const bf16x8*)&Kb[rbase + (kf ? kchunkB : kchunkA)];
                    s[kvt] = __builtin_amdgcn_mfma_f32_16x16x32_bf16(kfr, qf[kf], s[kvt], 0, 0, 0);
                }
            __builtin_amdgcn_s_setprio(0);

            // ---- causal mask: only the diagonal tile ----
            if (it == nIter - 1) {
                const int qq = wid * 16 + l16;
#pragma unroll
                for (int kvt = 0; kvt < 4; kvt++)
#pragma unroll
                    for (int r = 0; r < 4; r++)
                        if (kvt * 16 + quad * 4 + r > qq) s[kvt][r] = -1e30f;
            }

            // ---- p = exp2(s); pack per kvt; PV + l at K=32 over kvt-pairs p={0,1} ----
#pragma unroll
            for (int p = 0; p < 2; p++) {
                union { unsigned uu[4]; bf16x8 v; } pku;
#pragma unroll
                for (int half = 0; half < 2; half++) {
                    const int kvt = p * 2 + half;
                    float2 p01, p23;
                    p01.x = exp2_fast(s[kvt][0]);
                    p01.y = exp2_fast(s[kvt][1]);
                    p23.x = exp2_fast(s[kvt][2]);
                    p23.y = exp2_fast(s[kvt][3]);
                    __hip_bfloat162 lo = __float22bfloat162_rn(p01);
                    __hip_bfloat162 hi = __float22bfloat162_rn(p23);
                    pku.uu[half * 2 + 0] = *(unsigned*)&lo;
                    pku.uu[half * 2 + 1] = *(unsigned*)&hi;
                }
                const bf16x8 pk8 = pku.v;

                __builtin_amdgcn_s_setprio(1);
                ol = __builtin_amdgcn_mfma_f32_16x16x32_bf16(ones8, pk8, ol, 0, 0, 0);
#pragma unroll
                for (int dt = 0; dt < 4; dt++) {
                    // V A-frag slots quad*8+e: e<4 -> kv = p*32 + quad*4+e (chunk p*4+vq),
                    //                          e>=4 -> kv = p*32+16+quad*4+(e-4) (chunk p*4+2+vq)
                    const int base = (dt * 16 + l16) * 64;
                    union { bf16x4 h[2]; bf16x8 v; } vfu;
                    vfu.h[0] = *(const bf16x4*)&Vb[base + (((p * 4 + vq)     ^ (l16 & 7)) * 8) + vsub];
                    vfu.h[1] = *(const bf16x4*)&Vb[base + (((p * 4 + 2 + vq) ^ (l16 & 7)) * 8) + vsub];
                    o[dt] = __builtin_amdgcn_mfma_f32_16x16x32_bf16(vfu.v, pk8, o[dt], 0, 0, 0);
                }
                __builtin_amdgcn_s_setprio(0);
            }
        }

        // ---- epilogue: l complete per-lane; normalize + store O^T ----
        const float inv = 1.f / ol[0];
        bf16* obase = attn + (long)(b * 2048 + q0 + l16) * 1024 + h * 64;
#pragma unroll
        for (int dt = 0; dt < 4; dt++) {
            bf16 t4[4];
#pragma unroll
            for (int r = 0; r < 4; r++) t4[r] = __float2bfloat16(o[dt][r] * inv);
            *(uint2*)(obase + dt * 16 + quad * 4) = *(uint2*)t4;
        }
    }
}

// ---------------- launch ----------------
extern "C" void kernel_launch(void* const* d_in, const int* in_sizes, int n_in,
                              void* d_out, int out_size, void* d_ws, size_t ws_size,
                              hipStream_t stream) {
    const float* x  = (const float*)d_in[0];
    const float* wq = (const float*)d_in[1];
    const float* wk = (const float*)d_in[2];
    const float* wv = (const float*)d_in[3];
    const float* wo = (const float*)d_in[4];
    float* out = (float*)d_out;

    char* ws = (char*)d_ws;
    bf16* xb     = (bf16*)(ws);                       // 8192*1024
    bf16* wqkvT  = (bf16*)(ws + 16777216);            // 1536*1024
    bf16* woT    = (bf16*)(ws + 19922944);            // 1024*1024
    bf16* qkv    = (bf16*)(ws + 22020096);            // 8192*1536 (V region unused)
    bf16* vt     = (bf16*)(ws + 47185920);            // 4*4*64*2048
    bf16* attn   = (bf16*)(ws + 51380224);            // 8192*1024

    prolog_kernel<<<10752, 256, 0, stream>>>(x, wq, wk, wv, wo, xb, wqkvT, woT);

    gemm_bt<true, true><<<768, 256, 0, stream>>>(xb, wqkvT, qkv, vt, 8192, 1536, 1024);

    attn_kernel<<<dim3(16, 16, 4), 256, 0, stream>>>(qkv, vt, attn);

    gemm_bt<false, false><<<512, 256, 0, stream>>>(attn, woT, out, nullptr, 8192, 1024, 1024);
}

// Round 13
// 205.474 us; speedup vs baseline: 1.0829x; 1.0829x over previous
//
#include <hip/hip_runtime.h>
#include <hip/hip_bf16.h>

using bf16 = __hip_bfloat16;
typedef __attribute__((ext_vector_type(8))) short bf16x8;   // 8 bf16 in 4 VGPRs
typedef __attribute__((ext_vector_type(4))) short bf16x4;   // 4 bf16 in 2 VGPRs
typedef __attribute__((ext_vector_type(4))) float f32x4;

// async global->LDS, 16B per lane; LDS dest = wave-uniform base + lane*16
typedef const __attribute__((address_space(1))) void* as1_t;
typedef __attribute__((address_space(3))) void* as3_t;
__device__ __forceinline__ void load_lds16(const void* g, void* l) {
    __builtin_amdgcn_global_load_lds((as1_t)g, (as3_t)l, 16, 0, 0);
}

// exp2 as a single v_exp_f32 via COMPILER-VISIBLE builtin (verified v11: -12us, exact)
#if !__has_builtin(__builtin_amdgcn_exp2f)
extern "C" __device__ float __ocml_native_exp2_f32(float);
#endif
__device__ __forceinline__ float exp2_fast(float x) {
#if __has_builtin(__builtin_amdgcn_exp2f)
    return __builtin_amdgcn_exp2f(x);
#else
    return __ocml_native_exp2_f32(x);
#endif
}

// ---------------- merged prolog: x cast (blocks 0..8191) + 4 weight transposes ----------------
__global__ __launch_bounds__(256) void prolog_kernel(const float* __restrict__ x,
                                                     const float* __restrict__ wq,
                                                     const float* __restrict__ wk,
                                                     const float* __restrict__ wv,
                                                     const float* __restrict__ wo,
                                                     bf16* __restrict__ xb,
                                                     bf16* __restrict__ wqkvT,
                                                     bf16* __restrict__ woT) {
    __shared__ float tile[32][33];
    const int bxg = blockIdx.x;
    if (bxg < 8192) {
        // ---- cast f32 -> bf16 (x), 4 floats/thread ----
        const int i = bxg * 256 + threadIdx.x;
        const float4 v = *(const float4*)(x + (long)i * 4);
        bf16 t[4];
        t[0] = __float2bfloat16(v.x);
        t[1] = __float2bfloat16(v.y);
        t[2] = __float2bfloat16(v.z);
        t[3] = __float2bfloat16(v.w);
        *(uint2*)(xb + (long)i * 4) = *(uint2*)t;
        return;
    }
    // ---- transpose-cast: src[K=1024][N] f32 -> dst[N][1024] bf16 ----
    const int tcb = bxg - 8192;          // 0..2559
    const int bx  = tcb >> 5;            // 0..79
    const int k0  = (tcb & 31) * 32;
    const float* src; bf16* dst; int N, n0;
    if (bx < 32)      { src = wq; dst = wqkvT;              N = 1024; n0 = bx * 32; }
    else if (bx < 40) { src = wk; dst = wqkvT + 1024*1024;  N = 256;  n0 = (bx - 32) * 32; }
    else if (bx < 48) { src = wv; dst = wqkvT + 1280*1024;  N = 256;  n0 = (bx - 40) * 32; }
    else              { src = wo; dst = woT;                N = 1024; n0 = (bx - 48) * 32; }
    const int tx = threadIdx.x & 31;
    const int ty = threadIdx.x >> 5;   // 0..7
    for (int i = 0; i < 32; i += 8)
        tile[ty + i][tx] = src[(long)(k0 + ty + i) * N + n0 + tx];
    __syncthreads();
    for (int i = 0; i < 32; i += 8)
        dst[(long)(n0 + ty + i) * 1024 + k0 + tx] = __float2bfloat16(tile[tx][ty + i]);
}

// ---------------- GEMM v17 (unchanged): v14 loop + fused V^T epilogue ----------------
template <bool BF16_OUT, bool V_SPLIT>
__global__ __launch_bounds__(256) void gemm_bt(const bf16* __restrict__ A,
                                               const bf16* __restrict__ Bt,
                                               void* __restrict__ C,
                                               bf16* __restrict__ vt,
                                               int M, int N, int K) {
    __shared__ bf16 Ash[128 * 64];
    __shared__ bf16 Bsh[128 * 64];
    const int tid  = threadIdx.x;
    const int lane = tid & 63;
    const int wid  = tid >> 6;
    const int wm   = (wid >> 1) * 64;
    const int wn   = (wid & 1) * 64;
    const int quad = lane >> 4;
    const int l16  = lane & 15;

    // XCD-chunked swizzle (T1, bijective): XCD x owns swz in [x*per, (x+1)*per)
    const int nbn = N >> 7;
    const int nwg = (M >> 7) * nbn;
    const int per = nwg >> 3;
    const int wg  = blockIdx.x;
    const int swz = (wg & 7) * per + (wg >> 3);
    const int bm  = swz / nbn;          // bn innermost within each XCD chunk
    const int bn  = swz - bm * nbn;

    // staging: 4 rows/thread/matrix (rows rS+32m), 8 gload_lds per K-iter
    const int rS  = tid >> 3;                  // 0..31
    const int chS = tid & 7;                   // linear dest chunk
    const int gch = (chS ^ (rS & 7)) * 8;      // pre-swizzled source chunk (involution)

    const bf16* pa = A  + (long)(bm * 128 + rS) * K + gch;
    const bf16* pb = Bt + (long)(bn * 128 + rS) * K + gch;
    // wave-uniform LDS bases: wave w writes rows w*8..w*8+7 (+32m), lane*16B linear
    bf16* laB = Ash + (wid << 9);
    bf16* lbB = Bsh + (wid << 9);

    f32x4 acc[4][4] = {};

    for (int k0 = 0; k0 < K; k0 += 64) {
        __syncthreads();
#pragma unroll
        for (int m = 0; m < 4; m++) {
            load_lds16(pa + k0 + (long)(32 * m) * K, laB + m * 2048);
            load_lds16(pb + k0 + (long)(32 * m) * K, lbB + m * 2048);
        }
        __syncthreads();

#pragma unroll
        for (int kf = 0; kf < 2; kf++) {
            const int sw = ((kf * 4 + quad) ^ (l16 & 7)) * 8;
            bf16x8 af[4], bfr[4];
#pragma unroll
            for (int i = 0; i < 4; i++) af[i]  = *(const bf16x8*)&Ash[(wm + i * 16 + l16) * 64 + sw];
#pragma unroll
            for (int j = 0; j < 4; j++) bfr[j] = *(const bf16x8*)&Bsh[(wn + j * 16 + l16) * 64 + sw];
#pragma unroll
            for (int i = 0; i < 4; i++)
#pragma unroll
                for (int j = 0; j < 4; j++)
                    acc[i][j] = __builtin_amdgcn_mfma_f32_16x16x32_bf16(af[i], bfr[j], acc[i][j], 0, 0, 0);
        }
    }

    if (V_SPLIT && bn >= 10) {
        // ---- V columns: write vt[b*4+kvh][d][t] transposed, skip qkv ----
        const int kvh = (bn - 10) * 2 + (wn >> 6);
        const int bq  = bm >> 4;                 // batch index
        const int t0b = (bm & 15) * 128 + wm;    // token base within batch
        bf16* vbase = vt + ((long)(bq * 4 + kvh) * 64) * 2048;
#pragma unroll
        for (int i = 0; i < 4; i++) {
#pragma unroll
            for (int j = 0; j < 4; j++) {
                const int d  = j * 16 + l16;
                const int t0 = t0b + i * 16 + quad * 4;
                bf16 t4[4];
#pragma unroll
                for (int r = 0; r < 4; r++) t4[r] = __float2bfloat16(acc[i][j][r]);
                *(uint2*)(vbase + (long)d * 2048 + t0) = *(uint2*)t4;
            }
        }
        return;
    }

#pragma unroll
    for (int i = 0; i < 4; i++) {
#pragma unroll
        for (int r = 0; r < 4; r++) {
            const long row = (long)(bm * 128 + wm + i * 16 + quad * 4 + r);
#pragma unroll
            for (int j = 0; j < 4; j++) {
                const int col = bn * 128 + wn + j * 16 + l16;
                const float v = acc[i][j][r];
                if (BF16_OUT) ((bf16*)C)[row * N + col] = __float2bfloat16(v);
                else          ((float*)C)[row * N + col] = v;
            }
        }
    }
}

// ---------------- flash attention v13 (REVERTED from v14; best measured: 68.4us) ----------------
// v14's K=32 PV pairing regressed 68.4->82.0 (MfmaUtil 37->19): coarser dependency
// graph (8 exp + 4 packs + 2 ds_reads before each big MFMA) killed the fine
// VALU<->MFMA cross-pipe overlap that the per-kvt 16x16x16 path had. Lesson matches
// v15: this regime rewards fine interleave over issue-count reduction. v13 restored
// byte-identical: dbuf + one barrier/iter + builtin exp2 + setprio clusters.
__global__ __launch_bounds__(256) void attn_kernel(const bf16* __restrict__ qkv,
                                                   const bf16* __restrict__ vt,
                                                   bf16* __restrict__ attn) {
    __shared__ bf16 Ksh[2][64 * 64];  // [buf][kv][d], chunk ^= kv&7
    __shared__ bf16 Vsh[2][64 * 64];  // [buf][d][kv], chunk ^= d&7

    const int tid  = threadIdx.x;
    const int lane = tid & 63;
    const int wid  = tid >> 6;
    const int quad = lane >> 4;
    const int l16  = lane & 15;
    const int h    = blockIdx.y;
    const int b    = blockIdx.z;
    const int kvh  = h >> 2;
    const int pb   = blockIdx.x;      // 0..15

    const float ls = 0.125f * 1.44269504f;   // 1/sqrt(64) * log2(e)

    // ones fragment for l-accumulation MFMA (A[m][k] = 1.0)
    bf16x4 ones;
    { short o1 = (short)0x3F80; short t4[4] = {o1, o1, o1, o1}; ones = *(const bf16x4*)t4; }

    const bf16* kg = qkv + (long)(b * 2048) * 1536 + 1024 + kvh * 64;
    const bf16* vg = vt + (long)(b * 4 + kvh) * 64 * 2048;
    const int r0 = tid >> 3;          // 0..31
    const int ch0 = tid & 7;          // source 16B chunk 0..7
    const int c0 = ch0 * 8;

    const bf16* kp0 = kg + (long)r0 * 1536 + c0;
    const bf16* kp1 = kp0 + (long)32 * 1536;
    const bf16* vp0 = vg + (long)r0 * 2048 + c0;
    const bf16* vp1 = vp0 + (long)32 * 2048;

    // swizzled LDS write offsets (elements); (r0+32)&7 == r0&7
    const int wo0 = r0 * 64 + ((ch0 ^ (r0 & 7)) * 8);
    const int wo1 = wo0 + 32 * 64;
    // swizzled read address lane-constants
    const int kchunkA = (quad ^ (l16 & 7)) * 8;         // kf=0: chunk = quad
    const int kchunkB = ((4 + quad) ^ (l16 & 7)) * 8;   // kf=1: chunk = 4+quad
    const int vsub    = (quad & 1) * 4;                 // low/high half of 8-elem chunk
    const int vq      = quad >> 1;

#pragma unroll 1
    for (int seg = 0; seg < 2; ++seg) {
        const int qb     = seg ? pb : (31 - pb);
        const int qblock = qb * 64;
        const int q0     = qblock + wid * 16;

        // Q fragment (B-operand for S^T): n=q=l16, k=d=kf*32+quad*8+e; pre-scaled by ls
        const bf16* qbase = qkv + (long)(b * 2048 + q0 + l16) * 1536 + h * 64;
        bf16x8 qf[2];
#pragma unroll
        for (int kf = 0; kf < 2; kf++) {
            const bf16* qp = qbase + kf * 32 + quad * 8;
            bf16 t8[8];
#pragma unroll
            for (int e = 0; e < 8; e++) t8[e] = __float2bfloat16(__bfloat162float(qp[e]) * ls);
            qf[kf] = *(const bf16x8*)t8;
        }

        f32x4 o[4] = {};          // O^T: q=l16, d = dt*16 + quad*4 + r
        f32x4 ol = {};            // l accumulator: every element = sum_kv P[kv][q=l16]

        // prologue: prefetch tile 0 of this segment
        uint4 kr0 = *(const uint4*)kp0;
        uint4 kr1 = *(const uint4*)kp1;
        uint4 vr0 = *(const uint4*)vp0;
        uint4 vr1 = *(const uint4*)vp1;

        __syncthreads();   // segment boundary: prior segment's reads of both buffers done

        const int nIter = qb + 1;
        for (int it = 0; it < nIter; ++it) {
            bf16* __restrict__ Kb = &Ksh[it & 1][0];
            bf16* __restrict__ Vb = &Vsh[it & 1][0];
            *(uint4*)&Kb[wo0] = kr0;
            *(uint4*)&Kb[wo1] = kr1;
            *(uint4*)&Vb[wo0] = vr0;
            *(uint4*)&Vb[wo1] = vr1;
            __syncthreads();   // single barrier per iter; dbuf covers the WAR side

            // ---- prefetch tile it+1 (hides under compute below) ----
            if (it + 1 < nIter) {
                const long ko = (long)(it + 1) * 64 * 1536;
                const long vo = (it + 1) * 64;
                kr0 = *(const uint4*)(kp0 + ko);
                kr1 = *(const uint4*)(kp1 + ko);
                vr0 = *(const uint4*)(vp0 + vo);
                vr1 = *(const uint4*)(vp1 + vo);
            }

            // ---- S^T = K Q^T : s[kvt]: q=l16, kv = it*64 + kvt*16 + quad*4 + r ----
            f32x4 s[4] = {};
            __builtin_amdgcn_s_setprio(1);
#pragma unroll
            for (int kvt = 0; kvt < 4; kvt++)
#pragma unroll
                for (int kf = 0; kf < 2; kf++) {
                    const int rbase = (kvt * 16 + l16) * 64;
                    const bf16x8 kfr = *(const bf16x8*)&Kb[rbase + (kf ? kchunkB : kchunkA)];
                    s[kvt] = __builtin_amdgcn_mfma_f32_16x16x32_bf16(kfr, qf[kf], s[kvt], 0, 0, 0);
                }
            __builtin_amdgcn_s_setprio(0);

            // ---- causal mask: only the diagonal tile ----
            if (it == nIter - 1) {
                const int qq = wid * 16 + l16;
#pragma unroll
                for (int kvt = 0; kvt < 4; kvt++)
#pragma unroll
                    for (int r = 0; r < 4; r++)
                        if (kvt * 16 + quad * 4 + r > qq) s[kvt][r] = -1e30f;
            }

            // ---- p = exp2(s) [1 TRANS op each]; packed cvt; PV + l on matrix pipe ----
#pragma unroll
            for (int kvt = 0; kvt < 4; kvt++) {
                float2 p01, p23;
                p01.x = exp2_fast(s[kvt][0]);
                p01.y = exp2_fast(s[kvt][1]);
                p23.x = exp2_fast(s[kvt][2]);
                p23.y = exp2_fast(s[kvt][3]);
                __hip_bfloat162 pk01 = __float22bfloat162_rn(p01);
                __hip_bfloat162 pk23 = __float22bfloat162_rn(p23);
                bf16x4 pk;
                *(__hip_bfloat162*)&pk       = pk01;
                *((__hip_bfloat162*)&pk + 1) = pk23;

                __builtin_amdgcn_s_setprio(1);
                ol = __builtin_amdgcn_mfma_f32_16x16x16bf16_1k(ones, pk, ol, 0, 0, 0);
#pragma unroll
                for (int dt = 0; dt < 4; dt++) {
                    // V element (d = dt*16+l16, kv = kvt*16+quad*4+r):
                    // chunk = (kvt*2 + (quad>>1)) ^ (l16&7), sub = (quad&1)*4
                    const int vaddr = (dt * 16 + l16) * 64 +
                                      (((kvt * 2 + vq) ^ (l16 & 7)) * 8) + vsub;
                    const bf16x4 vf = *(const bf16x4*)&Vb[vaddr];
                    o[dt] = __builtin_amdgcn_mfma_f32_16x16x16bf16_1k(vf, pk, o[dt], 0, 0, 0);
                }
                __builtin_amdgcn_s_setprio(0);
            }
        }

        // ---- epilogue: l complete per-lane; normalize + store O^T ----
        const float inv = 1.f / ol[0];
        bf16* obase = attn + (long)(b * 2048 + q0 + l16) * 1024 + h * 64;
#pragma unroll
        for (int dt = 0; dt < 4; dt++) {
            bf16 t4[4];
#pragma unroll
            for (int r = 0; r < 4; r++) t4[r] = __float2bfloat16(o[dt][r] * inv);
            *(uint2*)(obase + dt * 16 + quad * 4) = *(uint2*)t4;
        }
    }
}

// ---------------- launch ----------------
extern "C" void kernel_launch(void* const* d_in, const int* in_sizes, int n_in,
                              void* d_out, int out_size, void* d_ws, size_t ws_size,
                              hipStream_t stream) {
    const float* x  = (const float*)d_in[0];
    const float* wq = (const float*)d_in[1];
    const float* wk = (const float*)d_in[2];
    const float* wv = (const float*)d_in[3];
    const float* wo = (const float*)d_in[4];
    float* out = (float*)d_out;

    char* ws = (char*)d_ws;
    bf16* xb     = (bf16*)(ws);                       // 8192*1024
    bf16* wqkvT  = (bf16*)(ws + 16777216);            // 1536*1024
    bf16* woT    = (bf16*)(ws + 19922944);            // 1024*1024
    bf16* qkv    = (bf16*)(ws + 22020096);            // 8192*1536 (V region unused)
    bf16* vt     = (bf16*)(ws + 47185920);            // 4*4*64*2048
    bf16* attn   = (bf16*)(ws + 51380224);            // 8192*1024

    prolog_kernel<<<10752, 256, 0, stream>>>(x, wq, wk, wv, wo, xb, wqkvT, woT);

    gemm_bt<true, true><<<768, 256, 0, stream>>>(xb, wqkvT, qkv, vt, 8192, 1536, 1024);

    attn_kernel<<<dim3(16, 16, 4), 256, 0, stream>>>(qkv, vt, attn);

    gemm_bt<false, false><<<512, 256, 0, stream>>>(attn, woT, out, nullptr, 8192, 1024, 1024);
}